// Round 2
// baseline (763.651 us; speedup 1.0000x reference)
//
#include <hip/hip_runtime.h>

// Reference dtypes (confirmed by round-1 NaN forensics): x/dna/bias/out = float32,
// hilbert_d = int32. Internally: W and X are cast to bf16 for the MFMA GEMM.
// x [4,2048,4096] f32, dna [6] f32, bias [4096] f32, hd [4096,4096] i32,
// out [4,2048,4096] f32.
#define M_DIM 4096
#define K_DIM 4096
#define NR_DIM 8192
#define TOTAL_ELEMS (M_DIM * K_DIM)

typedef unsigned short u16;
typedef unsigned int u32;
typedef __bf16 bf16x8 __attribute__((ext_vector_type(8)));
typedef float f32x4 __attribute__((ext_vector_type(4)));
typedef u16 u16x8 __attribute__((ext_vector_type(8)));

__device__ __forceinline__ u16 f2b(float f) {
    u32 v;
    __builtin_memcpy(&v, &f, sizeof(v));
    v += 0x7FFFu + ((v >> 16) & 1u);  // round-to-nearest-even
    return (u16)(v >> 16);
}

// Gielis superformula radius for one hilbert index. p[] = dna (f32).
// Generic powf path with runtime-uniform specializations (dna is wave-uniform:
// for the actual dna = [8.2,1,1,0.5,0.5,0.5] these become sqrt and x^-2).
__device__ __forceinline__ float compute_r(int d, const float* p) {
    const float C0 = (float)(6.283185307179586476925286766559 / 16777216.0); // 2*pi/2^24
    float theta = (float)d * C0;
    float ang = p[0] * theta * 0.25f;
    float s, c;
    sincosf(ang, &s, &c);
    float ca = fabsf(c / p[1]);
    float sb = fabsf(s / p[2]);
    float t1 = (p[4] == 0.5f) ? sqrtf(ca) : ((p[4] == 1.0f) ? ca : powf(ca, p[4]));
    float t2 = (p[5] == 0.5f) ? sqrtf(sb) : ((p[5] == 1.0f) ? sb : powf(sb, p[5]));
    float base = t1 + t2;
    float e = -1.0f / p[3];
    float r;
    if (e == -2.0f) { float ib = 1.0f / base; r = ib * ib; }
    else if (e == -1.0f) { r = 1.0f / base; }
    else { r = powf(base, e); }
    return r;
}

// Kernel 1: sum and sum-of-squares of r over all M*K elements (double atomics).
__global__ void __launch_bounds__(256) reduce_kernel(const int* __restrict__ hd,
                                                     const float* __restrict__ dna,
                                                     double* __restrict__ sums) {
    float p[6];
#pragma unroll
    for (int i = 0; i < 6; i++) p[i] = dna[i];

    double s = 0.0, s2 = 0.0;
    int idx = blockIdx.x * blockDim.x + threadIdx.x;
    int stride = gridDim.x * blockDim.x;
    for (int i = idx; i < TOTAL_ELEMS; i += stride) {
        float r = compute_r(hd[i], p);
        s += (double)r;
        s2 += (double)r * (double)r;
    }
#pragma unroll
    for (int off = 32; off > 0; off >>= 1) {
        s += __shfl_down(s, off);
        s2 += __shfl_down(s2, off);
    }
    __shared__ double ls[4], ls2[4];
    int lane = threadIdx.x & 63, w = threadIdx.x >> 6;
    if (lane == 0) { ls[w] = s; ls2[w] = s2; }
    __syncthreads();
    if (threadIdx.x == 0) {
        double a = ls[0] + ls[1] + ls[2] + ls[3];
        double b = ls2[0] + ls2[1] + ls2[2] + ls2[3];
        atomicAdd(&sums[0], a);
        atomicAdd(&sums[1], b);
    }
}

// Kernel 2: W[m,k] = (r - mean)/(std_ddof1 + 1e-9) * (1/sqrt(K)), stored bf16.
__global__ void __launch_bounds__(256) build_w_kernel(const int* __restrict__ hd,
                                                      const float* __restrict__ dna,
                                                      const double* __restrict__ sums,
                                                      u16* __restrict__ W) {
    float p[6];
#pragma unroll
    for (int i = 0; i < 6; i++) p[i] = dna[i];

    const double cnt = (double)TOTAL_ELEMS;
    double sum = sums[0], sumsq = sums[1];
    double mean_d = sum / cnt;
    double var_d = (sumsq - sum * sum / cnt) / (cnt - 1.0);
    float meanf = (float)mean_d;
    float stdf = (float)sqrt(var_d);
    const float scale = 0.015625f;  // 1/sqrt(4096) = 1/64
    float sc = scale / (stdf + 1e-9f);

    int idx = blockIdx.x * blockDim.x + threadIdx.x;
    int stride = gridDim.x * blockDim.x;
    for (int i = idx; i < TOTAL_ELEMS; i += stride) {
        float r = compute_r(hd[i], p);
        W[i] = f2b((r - meanf) * sc);
    }
}

// Kernel 3: x f32 -> bf16 (8 elements/thread, 32B in / 16B out per lane).
__global__ void __launch_bounds__(256) convert_x_kernel(const float* __restrict__ x,
                                                        u16* __restrict__ xb) {
    int i = (blockIdx.x * blockDim.x + threadIdx.x) * 8;
    const float4* xv = (const float4*)(x + i);
    float4 a = xv[0], b = xv[1];
    u16x8 o;
    o[0] = f2b(a.x); o[1] = f2b(a.y); o[2] = f2b(a.z); o[3] = f2b(a.w);
    o[4] = f2b(b.x); o[5] = f2b(b.y); o[6] = f2b(b.z); o[7] = f2b(b.w);
    *(u16x8*)(xb + i) = o;
}

// ---------------- GEMM: C[NR,M] = X[NR,K] * W[M,K]^T  (m97 structure) -------------
#define TM 128
#define TN 128
#define TK 64

__device__ __forceinline__ void gld_lds16(const u16* g, u16* l) {
    __builtin_amdgcn_global_load_lds(
        (const __attribute__((address_space(1))) void*)g,
        (__attribute__((address_space(3))) void*)l,
        16, 0, 0);
}

__global__ void __launch_bounds__(256) gemm_kernel(const u16* __restrict__ A,
                                                   const u16* __restrict__ B,
                                                   const float* __restrict__ bias,
                                                   float* __restrict__ C) {
    __shared__ __align__(16) u16 As[TM * TK];
    __shared__ __align__(16) u16 Bs[TN * TK];

    const int t = threadIdx.x;
    const int lane = t & 63;
    const int wave = t >> 6;
    const int wr = wave >> 1;   // 2x2 wave grid over the 128x128 tile
    const int wc = wave & 1;
    const int lrow = lane & 15; // A/B fragment m/n index, also C col
    const int lq = lane >> 4;   // quad: frag k-offset = lq*8; C row = lq*4+reg

    const long i0 = (long)blockIdx.y * TM;  // rows of C (x rows)
    const long j0 = (long)blockIdx.x * TN;  // cols of C (W rows)

    // staging: thread t covers 16B = 8 bf16 per issue; LDS dest = uniform + lane*16
    const int srow = t >> 3;        // [0,32)
    const int scol = (t & 7) * 8;   // {0..56}

    const f32x4 vzero = {0.f, 0.f, 0.f, 0.f};
    f32x4 acc[4][4];
#pragma unroll
    for (int a = 0; a < 4; a++)
#pragma unroll
        for (int b = 0; b < 4; b++) acc[a][b] = vzero;

    const u16* Ab = A + i0 * K_DIM;
    const u16* Bb = B + j0 * K_DIM;

    for (int k0 = 0; k0 < K_DIM; k0 += TK) {
#pragma unroll
        for (int q = 0; q < 4; q++) {
            int row = srow + q * 32;
            gld_lds16(Ab + (long)row * K_DIM + k0 + scol, &As[row * TK + scol]);
        }
#pragma unroll
        for (int q = 0; q < 4; q++) {
            int row = srow + q * 32;
            gld_lds16(Bb + (long)row * K_DIM + k0 + scol, &Bs[row * TK + scol]);
        }
        __syncthreads();

#pragma unroll
        for (int kk = 0; kk < TK; kk += 32) {
            bf16x8 af[4], bfr[4];
#pragma unroll
            for (int mi = 0; mi < 4; mi++)
                af[mi] = *(const bf16x8*)(&As[(wr * 64 + mi * 16 + lrow) * TK + kk + lq * 8]);
#pragma unroll
            for (int ni = 0; ni < 4; ni++)
                bfr[ni] = *(const bf16x8*)(&Bs[(wc * 64 + ni * 16 + lrow) * TK + kk + lq * 8]);
#pragma unroll
            for (int mi = 0; mi < 4; mi++)
#pragma unroll
                for (int ni = 0; ni < 4; ni++)
                    acc[mi][ni] = __builtin_amdgcn_mfma_f32_16x16x32_bf16(
                        af[mi], bfr[ni], acc[mi][ni], 0, 0, 0);
        }
        __syncthreads();
    }

    // Epilogue: C/D layout col=lane&15, row=lq*4+reg. Add bias, store f32.
#pragma unroll
    for (int ni = 0; ni < 4; ni++) {
        long j = j0 + wc * 64 + ni * 16 + lrow;
        float bv = bias[j];
#pragma unroll
        for (int mi = 0; mi < 4; mi++) {
            long ib = i0 + wr * 64 + mi * 16 + lq * 4;
#pragma unroll
            for (int r = 0; r < 4; r++) {
                C[(ib + r) * M_DIM + j] = acc[mi][ni][r] + bv;
            }
        }
    }
}

extern "C" void kernel_launch(void* const* d_in, const int* in_sizes, int n_in,
                              void* d_out, int out_size, void* d_ws, size_t ws_size,
                              hipStream_t stream) {
    const float* x = (const float*)d_in[0];    // f32 [4,2048,4096]
    const float* dna = (const float*)d_in[1];  // f32 [6]
    const float* bias = (const float*)d_in[2]; // f32 [4096]
    const int* hd = (const int*)d_in[3];       // i32 [4096,4096]
    float* out = (float*)d_out;                // f32 [4,2048,4096]

    double* sums = (double*)d_ws;                                   // 16 B
    u16* W = (u16*)((char*)d_ws + 256);                             // 32 MB bf16
    u16* Xb = (u16*)((char*)d_ws + 256 + (size_t)TOTAL_ELEMS * 2);  // 64 MB bf16

    hipMemsetAsync(d_ws, 0, 256, stream);  // zero the reduction accumulators
    reduce_kernel<<<dim3(1024), dim3(256), 0, stream>>>(hd, dna, sums);
    build_w_kernel<<<dim3(2048), dim3(256), 0, stream>>>(hd, dna, sums, W);
    convert_x_kernel<<<dim3((NR_DIM * K_DIM) / (256 * 8)), dim3(256), 0, stream>>>(x, Xb);
    gemm_kernel<<<dim3(M_DIM / TN, NR_DIM / TM), dim3(256), 0, stream>>>(Xb, W, bias, out);
}

// Round 3
// 625.284 us; speedup vs baseline: 1.2213x; 1.2213x over previous
//
#include <hip/hip_runtime.h>

// x [4,2048,4096] f32, dna [6] f32, bias [4096] f32, hd [4096,4096] i32,
// out [4,2048,4096] f32. Internally W and X are cast to bf16 for the MFMA GEMM.
#define M_DIM 4096
#define K_DIM 4096
#define NR_DIM 8192
#define TOTAL_ELEMS (M_DIM * K_DIM)

typedef unsigned short u16;
typedef unsigned int u32;
typedef __bf16 bf16x8 __attribute__((ext_vector_type(8)));
typedef float f32x4 __attribute__((ext_vector_type(4)));
typedef u16 u16x8 __attribute__((ext_vector_type(8)));

__device__ __forceinline__ u16 f2b(float f) {
    u32 v;
    __builtin_memcpy(&v, &f, sizeof(v));
    v += 0x7FFFu + ((v >> 16) & 1u);  // round-to-nearest-even
    return (u16)(v >> 16);
}

// Gielis superformula radius. c_ang = p0 * 2pi / 2^26 (precomputed in f64).
// Inline sincos: Cody-Waite 2-term reduction + deg-7/8 minimax polys. Only the
// MAGNITUDES of sin/cos are consumed (fabsf below), so quadrant handling
// reduces to a parity swap — signs are irrelevant.
__device__ __forceinline__ float compute_r(int d, const float* p, float c_ang) {
    float ang = (float)d * c_ang;
    float q = rintf(ang * 0.636619772f);            // x * 2/pi
    float r1 = fmaf(q, -1.57079637e+00f, ang);      // pi/2 = C1 + C2
    float r = fmaf(q, 4.37113883e-08f, r1);
    float r2 = r * r;
    float ts = fmaf(r2, -1.9840874e-04f, 8.3333310e-03f);
    ts = fmaf(r2, ts, -1.6666667e-01f);
    float sp = fmaf(r * r2, ts, r);                 // sin(r), r in [-pi/4,pi/4]
    float tc = fmaf(r2, -1.3888378e-03f, 4.1666638e-02f);
    tc = fmaf(r2, tc, -5.0e-01f);
    float cp = fmaf(r2, tc, 1.0f);                  // cos(r)
    int iq = (int)q;
    bool sw = (iq & 1) != 0;
    float s = sw ? cp : sp;
    float c = sw ? sp : cp;

    float ca = fabsf(c / p[1]);
    float sb = fabsf(s / p[2]);
    float t1 = (p[4] == 0.5f) ? sqrtf(ca) : ((p[4] == 1.0f) ? ca : powf(ca, p[4]));
    float t2 = (p[5] == 0.5f) ? sqrtf(sb) : ((p[5] == 1.0f) ? sb : powf(sb, p[5]));
    float base = t1 + t2;
    float e = -1.0f / p[3];
    float rr;
    if (e == -2.0f) { float ib = 1.0f / base; rr = ib * ib; }
    else if (e == -1.0f) { rr = 1.0f / base; }
    else { rr = powf(base, e); }
    return rr;
}

// Kernel 1: sum / sum-of-squares of r over the grid. The Hilbert d-index over
// the full 2^12 x 2^12 grid is a BIJECTION onto [0, 2^24), and mean/std are
// order-invariant, so we iterate d = linear index — no hd load needed.
__global__ void __launch_bounds__(256) reduce_kernel(const float* __restrict__ dna,
                                                     double* __restrict__ sums) {
    float p[6];
#pragma unroll
    for (int i = 0; i < 6; i++) p[i] = dna[i];
    float c_ang = (float)((double)p[0] * 6.283185307179586 / 67108864.0);

    double s = 0.0, s2 = 0.0;
    int idx = blockIdx.x * blockDim.x + threadIdx.x;
    int stride = gridDim.x * blockDim.x;
    for (int d = idx; d < TOTAL_ELEMS; d += stride) {
        float r = compute_r(d, p, c_ang);
        s += (double)r;
        s2 += (double)r * (double)r;
    }
#pragma unroll
    for (int off = 32; off > 0; off >>= 1) {
        s += __shfl_down(s, off);
        s2 += __shfl_down(s2, off);
    }
    __shared__ double ls[4], ls2[4];
    int lane = threadIdx.x & 63, w = threadIdx.x >> 6;
    if (lane == 0) { ls[w] = s; ls2[w] = s2; }
    __syncthreads();
    if (threadIdx.x == 0) {
        atomicAdd(&sums[0], ls[0] + ls[1] + ls[2] + ls[3]);
        atomicAdd(&sums[1], ls2[0] + ls2[1] + ls2[2] + ls2[3]);
    }
}

// Kernel 2: W[m,k] = (r - mean)/(std_ddof1 + 1e-9) * (1/sqrt(K)), stored bf16.
__global__ void __launch_bounds__(256) build_w_kernel(const int* __restrict__ hd,
                                                      const float* __restrict__ dna,
                                                      const double* __restrict__ sums,
                                                      u16* __restrict__ W) {
    float p[6];
#pragma unroll
    for (int i = 0; i < 6; i++) p[i] = dna[i];
    float c_ang = (float)((double)p[0] * 6.283185307179586 / 67108864.0);

    const double cnt = (double)TOTAL_ELEMS;
    double sum = sums[0], sumsq = sums[1];
    float meanf = (float)(sum / cnt);
    float stdf = (float)sqrt((sumsq - sum * sum / cnt) / (cnt - 1.0));
    float sc = 0.015625f / (stdf + 1e-9f);  // fold 1/sqrt(4096)

    int idx = blockIdx.x * blockDim.x + threadIdx.x;
    int stride = gridDim.x * blockDim.x;
    for (int i = idx * 4; i < TOTAL_ELEMS; i += stride * 4) {
        int4 d4 = *(const int4*)(hd + i);
        u16 o0 = f2b((compute_r(d4.x, p, c_ang) - meanf) * sc);
        u16 o1 = f2b((compute_r(d4.y, p, c_ang) - meanf) * sc);
        u16 o2 = f2b((compute_r(d4.z, p, c_ang) - meanf) * sc);
        u16 o3 = f2b((compute_r(d4.w, p, c_ang) - meanf) * sc);
        ushort4 o = {o0, o1, o2, o3};
        *(ushort4*)(W + i) = o;
    }
}

// Kernel 3: x f32 -> bf16 (8 elements/thread).
__global__ void __launch_bounds__(256) convert_x_kernel(const float* __restrict__ x,
                                                        u16* __restrict__ xb) {
    int i = (blockIdx.x * blockDim.x + threadIdx.x) * 8;
    const float4* xv = (const float4*)(x + i);
    float4 a = xv[0], b = xv[1];
    u16x8 o;
    o[0] = f2b(a.x); o[1] = f2b(a.y); o[2] = f2b(a.z); o[3] = f2b(a.w);
    o[4] = f2b(b.x); o[5] = f2b(b.y); o[6] = f2b(b.z); o[7] = f2b(b.w);
    *(u16x8*)(xb + i) = o;
}

// ---------------- GEMM: C[NR,M] = X[NR,K] * W[M,K]^T -----------------------
// m97 structure + XOR swizzle on 16B LDS chunks to kill the 16-way bank
// conflict (row stride 128 B == 32 banks). LDS[row][chunk ^ (row&7)] holds
// G[row][chunk]; global_load_lds dest is fixed at base+16*lane, so the
// swizzle is inverted on the global SOURCE address instead.
#define TM 128
#define TN 128
#define TK 64

__device__ __forceinline__ void gld_lds16(const u16* g, u16* l) {
    __builtin_amdgcn_global_load_lds(
        (const __attribute__((address_space(1))) void*)g,
        (__attribute__((address_space(3))) void*)l,
        16, 0, 0);
}

__global__ void __launch_bounds__(256) gemm_kernel(const u16* __restrict__ A,
                                                   const u16* __restrict__ B,
                                                   const float* __restrict__ bias,
                                                   float* __restrict__ C) {
    __shared__ __align__(16) u16 As[TM * TK];
    __shared__ __align__(16) u16 Bs[TN * TK];

    const int t = threadIdx.x;
    const int lane = t & 63;
    const int wave = t >> 6;
    const int wr = wave >> 1;   // 2x2 wave grid over the 128x128 tile
    const int wc = wave & 1;
    const int lrow = lane & 15; // fragment m/n index, also C col
    const int lq = lane >> 4;   // quad: frag k-chunk base; C row = lq*4+reg
    const int sw8 = lrow & 7;   // read-side swizzle key (row & 7 == lrow & 7)

    const long i0 = (long)blockIdx.y * TM;
    const long j0 = (long)blockIdx.x * TN;

    // staging: thread t fills LDS chunk t (16B). row = t>>3, lds chunk = t&7,
    // global chunk = (t&7) ^ (row&7)  (XOR is self-inverse).
    const int srow = t >> 3;                         // [0,32)
    const int scol = (((t & 7) ^ (srow & 7)) * 8);   // swizzled source col (u16)
    const int ldst = srow * TK + (t & 7) * 8;        // dest offset == 8*t

    const f32x4 vzero = {0.f, 0.f, 0.f, 0.f};
    f32x4 acc[4][4];
#pragma unroll
    for (int a = 0; a < 4; a++)
#pragma unroll
        for (int b = 0; b < 4; b++) acc[a][b] = vzero;

    const u16* Ab = A + i0 * K_DIM;
    const u16* Bb = B + j0 * K_DIM;

    for (int k0 = 0; k0 < K_DIM; k0 += TK) {
#pragma unroll
        for (int q = 0; q < 4; q++) {
            int row = srow + q * 32;
            gld_lds16(Ab + (long)row * K_DIM + k0 + scol, &As[ldst + q * 32 * TK]);
        }
#pragma unroll
        for (int q = 0; q < 4; q++) {
            int row = srow + q * 32;
            gld_lds16(Bb + (long)row * K_DIM + k0 + scol, &Bs[ldst + q * 32 * TK]);
        }
        __syncthreads();

#pragma unroll
        for (int kk = 0; kk < TK; kk += 32) {
            const int kc = (kk >> 3) + lq;  // global 16B-chunk index in row
            bf16x8 af[4], bfr[4];
#pragma unroll
            for (int mi = 0; mi < 4; mi++) {
                int row = wr * 64 + mi * 16 + lrow;
                af[mi] = *(const bf16x8*)(&As[row * TK + ((kc ^ sw8) << 3)]);
            }
#pragma unroll
            for (int ni = 0; ni < 4; ni++) {
                int row = wc * 64 + ni * 16 + lrow;
                bfr[ni] = *(const bf16x8*)(&Bs[row * TK + ((kc ^ sw8) << 3)]);
            }
#pragma unroll
            for (int mi = 0; mi < 4; mi++)
#pragma unroll
                for (int ni = 0; ni < 4; ni++)
                    acc[mi][ni] = __builtin_amdgcn_mfma_f32_16x16x32_bf16(
                        af[mi], bfr[ni], acc[mi][ni], 0, 0, 0);
        }
        __syncthreads();
    }

    // Epilogue: C/D layout col=lane&15, row=lq*4+reg. Add bias, store f32.
#pragma unroll
    for (int ni = 0; ni < 4; ni++) {
        long j = j0 + wc * 64 + ni * 16 + lrow;
        float bv = bias[j];
#pragma unroll
        for (int mi = 0; mi < 4; mi++) {
            long ib = i0 + wr * 64 + mi * 16 + lq * 4;
#pragma unroll
            for (int r = 0; r < 4; r++) {
                C[(ib + r) * M_DIM + j] = acc[mi][ni][r] + bv;
            }
        }
    }
}

extern "C" void kernel_launch(void* const* d_in, const int* in_sizes, int n_in,
                              void* d_out, int out_size, void* d_ws, size_t ws_size,
                              hipStream_t stream) {
    const float* x = (const float*)d_in[0];    // f32 [4,2048,4096]
    const float* dna = (const float*)d_in[1];  // f32 [6]
    const float* bias = (const float*)d_in[2]; // f32 [4096]
    const int* hd = (const int*)d_in[3];       // i32 [4096,4096]
    float* out = (float*)d_out;                // f32 [4,2048,4096]

    double* sums = (double*)d_ws;                                   // 16 B
    u16* W = (u16*)((char*)d_ws + 256);                             // 32 MB bf16
    u16* Xb = (u16*)((char*)d_ws + 256 + (size_t)TOTAL_ELEMS * 2);  // 64 MB bf16

    hipMemsetAsync(d_ws, 0, 256, stream);
    reduce_kernel<<<dim3(1024), dim3(256), 0, stream>>>(dna, sums);
    build_w_kernel<<<dim3(2048), dim3(256), 0, stream>>>(hd, dna, sums, W);
    convert_x_kernel<<<dim3((NR_DIM * K_DIM) / (256 * 8)), dim3(256), 0, stream>>>(x, Xb);
    gemm_kernel<<<dim3(M_DIM / TN, NR_DIM / TM), dim3(256), 0, stream>>>(Xb, W, bias, out);
}

// Round 4
// 601.623 us; speedup vs baseline: 1.2693x; 1.0393x over previous
//
#include <hip/hip_runtime.h>

// x [4,2048,4096] f32, dna [6] f32, bias [4096] f32, hd [4096,4096] i32,
// out [4,2048,4096] f32. Internally W and X are cast to bf16 for the MFMA GEMM.
#define M_DIM 4096
#define K_DIM 4096
#define NR_DIM 8192
#define TOTAL_ELEMS (M_DIM * K_DIM)

typedef unsigned short u16;
typedef unsigned int u32;
typedef __bf16 bf16x8 __attribute__((ext_vector_type(8)));
typedef float f32x4 __attribute__((ext_vector_type(4)));
typedef u16 u16x8 __attribute__((ext_vector_type(8)));

__device__ __forceinline__ u16 f2b(float f) {
    u32 v;
    __builtin_memcpy(&v, &f, sizeof(v));
    v += 0x7FFFu + ((v >> 16) & 1u);  // round-to-nearest-even
    return (u16)(v >> 16);
}

// Inline |sin|,|cos| via Cody-Waite + minimax polys. Signs are irrelevant
// downstream (fabs), so quadrant handling is a parity swap only.
__device__ __forceinline__ void abs_sincos(float ang, float* s, float* c) {
    float q = rintf(ang * 0.636619772f);
    float r1 = fmaf(q, -1.57079637e+00f, ang);
    float r = fmaf(q, 4.37113883e-08f, r1);
    float r2 = r * r;
    float ts = fmaf(r2, -1.9840874e-04f, 8.3333310e-03f);
    ts = fmaf(r2, ts, -1.6666667e-01f);
    float sp = fmaf(r * r2, ts, r);
    float tc = fmaf(r2, -1.3888378e-03f, 4.1666638e-02f);
    tc = fmaf(r2, tc, -5.0e-01f);
    float cp = fmaf(r2, tc, 1.0f);
    bool sw = (((int)q) & 1) != 0;
    *s = sw ? cp : sp;
    *c = sw ? sp : cp;
}

// FAST path, valid when a==b==1, n1==n2==n3==0.5 (the actual dna):
// r = 1 / (sqrt|cos| + sqrt|sin|)^2. base in [1, 1.68] — no singularity.
// v_sqrt_f32 / v_rcp_f32 are ~1 ulp; tolerance is 2% relative.
__device__ __forceinline__ float compute_r_fast(int d, float c_ang) {
    float s, c;
    abs_sincos((float)d * c_ang, &s, &c);
    float base = __builtin_amdgcn_sqrtf(fabsf(c)) + __builtin_amdgcn_sqrtf(fabsf(s));
    return __builtin_amdgcn_rcpf(base * base);
}

// GENERIC path for arbitrary dna (powf etc.) — wave-uniform-selected, cold.
__device__ __noinline__ float compute_r_gen(int d, float c_ang, float inv_a,
                                            float inv_b, float n2, float n3, float e) {
    float s, c;
    abs_sincos((float)d * c_ang, &s, &c);
    float ca = fabsf(c) * fabsf(inv_a);
    float sb = fabsf(s) * fabsf(inv_b);
    float t1 = (n2 == 0.5f) ? sqrtf(ca) : ((n2 == 1.0f) ? ca : powf(ca, n2));
    float t2 = (n3 == 0.5f) ? sqrtf(sb) : ((n3 == 1.0f) ? sb : powf(sb, n3));
    float base = t1 + t2;
    if (e == -2.0f) { float ib = __builtin_amdgcn_rcpf(base); return ib * ib; }
    if (e == -1.0f) return __builtin_amdgcn_rcpf(base);
    return powf(base, e);
}

__device__ __forceinline__ bool dna_is_fast(const float* p) {
    return (p[1] == 1.0f) & (p[2] == 1.0f) & (p[3] == 0.5f) &
           (p[4] == 0.5f) & (p[5] == 0.5f);
}

// Kernel 1: sum / sum-of-squares of r. Hilbert d over the full 2^12 x 2^12
// grid is a bijection onto [0,2^24) and mean/std are order-invariant, so we
// iterate d = linear index — no hd load.
__global__ void __launch_bounds__(256) reduce_kernel(const float* __restrict__ dna,
                                                     double* __restrict__ sums) {
    float p[6];
#pragma unroll
    for (int i = 0; i < 6; i++) p[i] = dna[i];
    float c_ang = (float)((double)p[0] * 6.283185307179586 / 67108864.0);

    double s = 0.0, s2 = 0.0;
    int idx = blockIdx.x * blockDim.x + threadIdx.x;
    int stride = gridDim.x * blockDim.x;
    if (dna_is_fast(p)) {
        for (int d = idx; d < TOTAL_ELEMS; d += stride) {
            float r = compute_r_fast(d, c_ang);
            s += (double)r;
            s2 += (double)r * (double)r;
        }
    } else {
        float inv_a = 1.0f / p[1], inv_b = 1.0f / p[2], e = -1.0f / p[3];
        for (int d = idx; d < TOTAL_ELEMS; d += stride) {
            float r = compute_r_gen(d, c_ang, inv_a, inv_b, p[4], p[5], e);
            s += (double)r;
            s2 += (double)r * (double)r;
        }
    }
#pragma unroll
    for (int off = 32; off > 0; off >>= 1) {
        s += __shfl_down(s, off);
        s2 += __shfl_down(s2, off);
    }
    __shared__ double ls[4], ls2[4];
    int lane = threadIdx.x & 63, w = threadIdx.x >> 6;
    if (lane == 0) { ls[w] = s; ls2[w] = s2; }
    __syncthreads();
    if (threadIdx.x == 0) {
        atomicAdd(&sums[0], ls[0] + ls[1] + ls[2] + ls[3]);
        atomicAdd(&sums[1], ls2[0] + ls2[1] + ls2[2] + ls2[3]);
    }
}

// Kernel 2: W[m,k] = (r - mean)/(std_ddof1 + 1e-9) * (1/sqrt(K)), stored bf16.
__global__ void __launch_bounds__(256) build_w_kernel(const int* __restrict__ hd,
                                                      const float* __restrict__ dna,
                                                      const double* __restrict__ sums,
                                                      u16* __restrict__ W) {
    float p[6];
#pragma unroll
    for (int i = 0; i < 6; i++) p[i] = dna[i];
    float c_ang = (float)((double)p[0] * 6.283185307179586 / 67108864.0);

    const double cnt = (double)TOTAL_ELEMS;
    double sum = sums[0], sumsq = sums[1];
    float meanf = (float)(sum / cnt);
    float stdf = (float)sqrt((sumsq - sum * sum / cnt) / (cnt - 1.0));
    float sc = 0.015625f / (stdf + 1e-9f);  // fold 1/sqrt(4096)

    int idx = blockIdx.x * blockDim.x + threadIdx.x;
    int stride = gridDim.x * blockDim.x;
    if (dna_is_fast(p)) {
        for (int i = idx * 4; i < TOTAL_ELEMS; i += stride * 4) {
            int4 d4 = *(const int4*)(hd + i);
            ushort4 o;
            o.x = f2b((compute_r_fast(d4.x, c_ang) - meanf) * sc);
            o.y = f2b((compute_r_fast(d4.y, c_ang) - meanf) * sc);
            o.z = f2b((compute_r_fast(d4.z, c_ang) - meanf) * sc);
            o.w = f2b((compute_r_fast(d4.w, c_ang) - meanf) * sc);
            *(ushort4*)(W + i) = o;
        }
    } else {
        float inv_a = 1.0f / p[1], inv_b = 1.0f / p[2], e = -1.0f / p[3];
        for (int i = idx * 4; i < TOTAL_ELEMS; i += stride * 4) {
            int4 d4 = *(const int4*)(hd + i);
            ushort4 o;
            o.x = f2b((compute_r_gen(d4.x, c_ang, inv_a, inv_b, p[4], p[5], e) - meanf) * sc);
            o.y = f2b((compute_r_gen(d4.y, c_ang, inv_a, inv_b, p[4], p[5], e) - meanf) * sc);
            o.z = f2b((compute_r_gen(d4.z, c_ang, inv_a, inv_b, p[4], p[5], e) - meanf) * sc);
            o.w = f2b((compute_r_gen(d4.w, c_ang, inv_a, inv_b, p[4], p[5], e) - meanf) * sc);
            *(ushort4*)(W + i) = o;
        }
    }
}

// Kernel 3: x f32 -> bf16 (8 elements/thread).
__global__ void __launch_bounds__(256) convert_x_kernel(const float* __restrict__ x,
                                                        u16* __restrict__ xb) {
    int i = (blockIdx.x * blockDim.x + threadIdx.x) * 8;
    const float4* xv = (const float4*)(x + i);
    float4 a = xv[0], b = xv[1];
    u16x8 o;
    o[0] = f2b(a.x); o[1] = f2b(a.y); o[2] = f2b(a.z); o[3] = f2b(a.w);
    o[4] = f2b(b.x); o[5] = f2b(b.y); o[6] = f2b(b.z); o[7] = f2b(b.w);
    *(u16x8*)(xb + i) = o;
}

// ---------------- GEMM: C[NR,M] = X[NR,K] * W[M,K]^T -----------------------
// m97 structure + XOR swizzle on 16B LDS chunks (round 3: conflicts -> 0).
// UNCHANGED this round — serves as the control dispatch.
#define TM 128
#define TN 128
#define TK 64

__device__ __forceinline__ void gld_lds16(const u16* g, u16* l) {
    __builtin_amdgcn_global_load_lds(
        (const __attribute__((address_space(1))) void*)g,
        (__attribute__((address_space(3))) void*)l,
        16, 0, 0);
}

__global__ void __launch_bounds__(256) gemm_kernel(const u16* __restrict__ A,
                                                   const u16* __restrict__ B,
                                                   const float* __restrict__ bias,
                                                   float* __restrict__ C) {
    __shared__ __align__(16) u16 As[TM * TK];
    __shared__ __align__(16) u16 Bs[TN * TK];

    const int t = threadIdx.x;
    const int lane = t & 63;
    const int wave = t >> 6;
    const int wr = wave >> 1;
    const int wc = wave & 1;
    const int lrow = lane & 15;
    const int lq = lane >> 4;
    const int sw8 = lrow & 7;

    const long i0 = (long)blockIdx.y * TM;
    const long j0 = (long)blockIdx.x * TN;

    const int srow = t >> 3;
    const int scol = (((t & 7) ^ (srow & 7)) * 8);
    const int ldst = srow * TK + (t & 7) * 8;

    const f32x4 vzero = {0.f, 0.f, 0.f, 0.f};
    f32x4 acc[4][4];
#pragma unroll
    for (int a = 0; a < 4; a++)
#pragma unroll
        for (int b = 0; b < 4; b++) acc[a][b] = vzero;

    const u16* Ab = A + i0 * K_DIM;
    const u16* Bb = B + j0 * K_DIM;

    for (int k0 = 0; k0 < K_DIM; k0 += TK) {
#pragma unroll
        for (int q = 0; q < 4; q++) {
            int row = srow + q * 32;
            gld_lds16(Ab + (long)row * K_DIM + k0 + scol, &As[ldst + q * 32 * TK]);
        }
#pragma unroll
        for (int q = 0; q < 4; q++) {
            int row = srow + q * 32;
            gld_lds16(Bb + (long)row * K_DIM + k0 + scol, &Bs[ldst + q * 32 * TK]);
        }
        __syncthreads();

#pragma unroll
        for (int kk = 0; kk < TK; kk += 32) {
            const int kc = (kk >> 3) + lq;
            bf16x8 af[4], bfr[4];
#pragma unroll
            for (int mi = 0; mi < 4; mi++) {
                int row = wr * 64 + mi * 16 + lrow;
                af[mi] = *(const bf16x8*)(&As[row * TK + ((kc ^ sw8) << 3)]);
            }
#pragma unroll
            for (int ni = 0; ni < 4; ni++) {
                int row = wc * 64 + ni * 16 + lrow;
                bfr[ni] = *(const bf16x8*)(&Bs[row * TK + ((kc ^ sw8) << 3)]);
            }
#pragma unroll
            for (int mi = 0; mi < 4; mi++)
#pragma unroll
                for (int ni = 0; ni < 4; ni++)
                    acc[mi][ni] = __builtin_amdgcn_mfma_f32_16x16x32_bf16(
                        af[mi], bfr[ni], acc[mi][ni], 0, 0, 0);
        }
        __syncthreads();
    }

#pragma unroll
    for (int ni = 0; ni < 4; ni++) {
        long j = j0 + wc * 64 + ni * 16 + lrow;
        float bv = bias[j];
#pragma unroll
        for (int mi = 0; mi < 4; mi++) {
            long ib = i0 + wr * 64 + mi * 16 + lq * 4;
#pragma unroll
            for (int r = 0; r < 4; r++) {
                C[(ib + r) * M_DIM + j] = acc[mi][ni][r] + bv;
            }
        }
    }
}

extern "C" void kernel_launch(void* const* d_in, const int* in_sizes, int n_in,
                              void* d_out, int out_size, void* d_ws, size_t ws_size,
                              hipStream_t stream) {
    const float* x = (const float*)d_in[0];
    const float* dna = (const float*)d_in[1];
    const float* bias = (const float*)d_in[2];
    const int* hd = (const int*)d_in[3];
    float* out = (float*)d_out;

    double* sums = (double*)d_ws;                                   // 16 B
    u16* W = (u16*)((char*)d_ws + 256);                             // 32 MB bf16
    u16* Xb = (u16*)((char*)d_ws + 256 + (size_t)TOTAL_ELEMS * 2);  // 64 MB bf16

    hipMemsetAsync(d_ws, 0, 256, stream);
    reduce_kernel<<<dim3(1024), dim3(256), 0, stream>>>(dna, sums);
    build_w_kernel<<<dim3(2048), dim3(256), 0, stream>>>(hd, dna, sums, W);
    convert_x_kernel<<<dim3((NR_DIM * K_DIM) / (256 * 8)), dim3(256), 0, stream>>>(x, Xb);
    gemm_kernel<<<dim3(M_DIM / TN, NR_DIM / TM), dim3(256), 0, stream>>>(Xb, W, bias, out);
}